// Round 1
// baseline (247.550 us; speedup 1.0000x reference)
//
#include <hip/hip_runtime.h>

#define SDIM 500
#define DDIM 64
#define NTHREADS 256

__global__ __launch_bounds__(NTHREADS) void rs_main(
    const int* __restrict__ need_replace,    // (N,2)
    const float* __restrict__ union_feature, // (N,128)
    const float* __restrict__ all_items,     // (n_items,64)
    const int* __restrict__ sample_items,    // (n_users,500)
    const float* __restrict__ Wm,            // (64,128)
    const float* __restrict__ bv,            // (64)
    const float* __restrict__ gumbel_u,      // (N,500)
    float* __restrict__ out_items,           // (N)   as float
    float* __restrict__ out_feat,            // (N,64)
    float* __restrict__ ws_sim)              // (N)   similarity per row
{
    __shared__ float s_uf[128];
    __shared__ float s_item[DDIM];
    __shared__ float s_uif[DDIM];
    __shared__ float s_rank[SDIM];   // rank_score
    __shared__ float s_key[SDIM];    // replace_score + gumbel
    __shared__ int   s_samp[SDIM];
    __shared__ int   s_pos[SDIM];    // stable ascending rank of each element
    __shared__ float s_rv[NTHREADS];
    __shared__ int   s_ri[NTHREADS];
    __shared__ int   s_jstar;

    const int n   = blockIdx.x;
    const int tid = threadIdx.x;
    const int user = need_replace[2 * n];
    const int item = need_replace[2 * n + 1];

    // stage union_feature row and item embedding
    if (tid < 128) s_uf[tid] = union_feature[(long)n * 128 + tid];
    if (tid >= 128 && tid < 128 + DDIM)
        s_item[tid - 128] = all_items[(long)item * DDIM + (tid - 128)];
    __syncthreads();

    // uif = W @ uf + b   (64 outputs, 128-length dots)
    if (tid < DDIM) {
        float acc = bv[tid];
        const float* wr = Wm + (long)tid * 128;
        #pragma unroll 8
        for (int j = 0; j < 128; ++j) acc += wr[j] * s_uf[j];
        s_uif[tid] = acc;
    }
    __syncthreads();

    // scores for each sample
    const int*   samp_row = sample_items + (long)user * SDIM;
    const float* gu_row   = gumbel_u + (long)n * SDIM;
    for (int s = tid; s < SDIM; s += NTHREADS) {
        int idx = samp_row[s];
        s_samp[s] = idx;
        const float4* fr = (const float4*)(all_items + (long)idx * DDIM);
        float a0 = 0.f, a1 = 0.f;
        #pragma unroll
        for (int e4 = 0; e4 < DDIM / 4; ++e4) {
            float4 f = fr[e4];
            int e = e4 * 4;
            a0 += f.x * s_item[e] + f.y * s_item[e + 1] + f.z * s_item[e + 2] + f.w * s_item[e + 3];
            a1 += f.x * s_uif[e]  + f.y * s_uif[e + 1]  + f.z * s_uif[e + 2]  + f.w * s_uif[e + 3];
        }
        float u = gu_row[s];
        // g = -log(-log(u*(1-2eps)+eps)), eps=1e-7, fp32 like JAX
        float g = -logf(-logf(u * (1.0f - 2e-7f) + 1e-7f));
        s_rank[s] = a0;
        s_key[s]  = a1 + g;
    }
    __syncthreads();

    // argmax over s_key with first-max tie-break (matches jnp.argmax)
    {
        float bvv = -__builtin_inff();
        int   bii = SDIM;
        for (int s = tid; s < SDIM; s += NTHREADS) {
            float v = s_key[s];
            if (v > bvv) { bvv = v; bii = s; }  // ascending scan keeps first
        }
        s_rv[tid] = bvv; s_ri[tid] = bii;
        __syncthreads();
        for (int off = NTHREADS / 2; off > 0; off >>= 1) {
            if (tid < off) {
                float v2 = s_rv[tid + off]; int i2 = s_ri[tid + off];
                if (v2 > s_rv[tid] || (v2 == s_rv[tid] && i2 < s_ri[tid])) {
                    s_rv[tid] = v2; s_ri[tid] = i2;
                }
            }
            __syncthreads();
        }
    }
    const int k = s_ri[0];

    // stable ascending ranks: pos[j] = #{t: v[t] < v[j]} + #{t<j: v[t]==v[j]}
    for (int j = tid; j < SDIM; j += NTHREADS) {
        float vj = s_rank[j];
        int cnt = 0;
        for (int t = 0; t < SDIM; ++t) {
            float vt = s_rank[t];
            cnt += (vt < vj) | ((vt == vj) & (t < j));
        }
        s_pos[j] = cnt;
    }
    __syncthreads();
    // find j* with rank(j*) == k  (ranks form a permutation: unique)
    for (int j = tid; j < SDIM; j += NTHREADS) {
        if (s_pos[j] == k) s_jstar = j;
    }
    __syncthreads();

    if (tid == 0) {
        out_items[n] = (float)s_samp[s_jstar];
        float sim = (float)(s_pos[k] + 1) / (float)SDIM;
        ws_sim[n] = sim;
    }
    // replaceable_items_feature = all_items[samp[k]]
    const int src = s_samp[k];
    if (tid < DDIM)
        out_feat[(long)n * DDIM + tid] = all_items[(long)src * DDIM + tid];
}

__global__ __launch_bounds__(NTHREADS) void rs_reduce(
    const float* __restrict__ ws_sim, float* __restrict__ out_scal, int N)
{
    __shared__ float s0[NTHREADS], s1[NTHREADS];
    int tid = threadIdx.x;
    float a = 0.f, m = 0.f;
    for (int i = tid; i < N; i += NTHREADS) {
        float sim = ws_sim[i];
        a += fabsf(sim - 0.5f);
        m += sim;
    }
    s0[tid] = a; s1[tid] = m;
    __syncthreads();
    for (int off = NTHREADS / 2; off > 0; off >>= 1) {
        if (tid < off) { s0[tid] += s0[tid + off]; s1[tid] += s1[tid + off]; }
        __syncthreads();
    }
    if (tid == 0) {
        out_scal[0] = s0[0] / (float)N;  // similarity_loss
        out_scal[1] = s1[0] / (float)N;  // mean(similarity)
    }
}

extern "C" void kernel_launch(void* const* d_in, const int* in_sizes, int n_in,
                              void* d_out, int out_size, void* d_ws, size_t ws_size,
                              hipStream_t stream) {
    const int*   need_replace  = (const int*)d_in[0];
    const float* union_feature = (const float*)d_in[1];
    const float* all_items     = (const float*)d_in[2];
    const int*   sample_items  = (const int*)d_in[3];
    const float* Wm            = (const float*)d_in[4];
    const float* bv            = (const float*)d_in[5];
    const float* gumbel_u      = (const float*)d_in[6];

    const int N = in_sizes[0] / 2;  // 4096

    float* out       = (float*)d_out;
    float* out_items = out;                 // N
    float* out_feat  = out + N;             // N*64
    float* out_scal  = out + N + (long)N * DDIM;  // 2 scalars
    float* ws_sim    = (float*)d_ws;        // N floats

    rs_main<<<N, NTHREADS, 0, stream>>>(need_replace, union_feature, all_items,
                                        sample_items, Wm, bv, gumbel_u,
                                        out_items, out_feat, ws_sim);
    rs_reduce<<<1, NTHREADS, 0, stream>>>(ws_sim, out_scal, N);
}

// Round 2
// 127.468 us; speedup vs baseline: 1.9421x; 1.9421x over previous
//
#include <hip/hip_runtime.h>

#define SDIM 500
#define DDIM 64
#define NT   256

__device__ __forceinline__ unsigned int ford(float x) {
    unsigned int u = __float_as_uint(x);
    return u ^ ((unsigned)((int)u >> 31) | 0x80000000u);
}

__global__ __launch_bounds__(NT) void rs_main(
    const int* __restrict__ need_replace,    // (N,2)
    const float* __restrict__ union_feature, // (N,128)
    const float* __restrict__ all_items,     // (n_items,64)
    const int* __restrict__ sample_items,    // (n_users,500)
    const float* __restrict__ Wm,            // (64,128)
    const float* __restrict__ bv,            // (64)
    const float* __restrict__ gumbel_u,      // (N,500)
    float* __restrict__ out_items,           // (N)
    float* __restrict__ out_feat,            // (N,64)
    float* __restrict__ ws_sim)              // (N)
{
    __shared__ __align__(16) float s_uf[128];
    __shared__ __align__(16) float s_item[DDIM];
    __shared__ __align__(16) float s_uif[DDIM];
    __shared__ __align__(16) unsigned long long s_w[SDIM]; // stable-rank keys
    __shared__ float s_key[SDIM];   // replace_score (+gumbel)
    __shared__ int   s_samp[SDIM];
    __shared__ int   s_pos[SDIM];
    __shared__ float s_rv[NT];
    __shared__ int   s_ri[NT];
    __shared__ int   s_jstar;

    const int n   = blockIdx.x;
    const int tid = threadIdx.x;
    const int user = need_replace[2 * n];
    const int item = need_replace[2 * n + 1];

    // stage union_feature row + item embedding (coalesced)
    if (tid < 128) s_uf[tid] = union_feature[(long)n * 128 + tid];
    else if (tid < 128 + DDIM) s_item[tid - 128] = all_items[(long)item * DDIM + (tid - 128)];
    const int* samp_row = sample_items + (long)user * SDIM;
    for (int s = tid; s < SDIM; s += NT) s_samp[s] = samp_row[s];
    __syncthreads();

    // uif = W @ uf + b : 4 lanes per output row, coalesced W reads
    {
        const int row = tid >> 2, part = tid & 3;
        const float4* wr4 = (const float4*)(Wm + (long)row * 128);
        const float4* uf4 = (const float4*)s_uf;
        float acc = 0.f;
        #pragma unroll
        for (int q = 0; q < 8; ++q) {
            float4 w4 = wr4[part + q * 4];
            float4 u4 = uf4[part + q * 4];
            acc += w4.x * u4.x + w4.y * u4.y + w4.z * u4.z + w4.w * u4.w;
        }
        acc += __shfl_xor(acc, 1);
        acc += __shfl_xor(acc, 2);
        if (part == 0) s_uif[row] = acc + bv[row];
    }
    __syncthreads();

    // scores: 16 lanes per sample row, coalesced gathers, shfl-tree dots
    {
        const int grp = tid >> 4, lane16 = tid & 15;
        const float4 wi = ((const float4*)s_item)[lane16];
        const float4 wu = ((const float4*)s_uif)[lane16];
        for (int s0 = 0; s0 < SDIM; s0 += 16) {
            int s = s0 + grp;
            float a0 = 0.f, a1 = 0.f;
            if (s < SDIM) {
                int idx = s_samp[s];
                float4 f = ((const float4*)(all_items + (long)idx * DDIM))[lane16];
                a0 = f.x * wi.x + f.y * wi.y + f.z * wi.z + f.w * wi.w;
                a1 = f.x * wu.x + f.y * wu.y + f.z * wu.z + f.w * wu.w;
            }
            #pragma unroll
            for (int off = 8; off >= 1; off >>= 1) {
                a0 += __shfl_xor(a0, off);
                a1 += __shfl_xor(a1, off);
            }
            if (s < SDIM && lane16 == 0) {
                s_w[s]   = ((unsigned long long)ford(a0) << 32) | (unsigned)s;
                s_key[s] = a1;
            }
        }
    }
    __syncthreads();

    // add gumbel noise (same fp expression as reference)
    const float* gu_row = gumbel_u + (long)n * SDIM;
    for (int s = tid; s < SDIM; s += NT) {
        float u = gu_row[s];
        float g = -logf(-logf(u * (1.0f - 2e-7f) + 1e-7f));
        s_key[s] += g;
    }
    __syncthreads();

    // argmax over s_key, first-max tie-break (matches jnp.argmax)
    {
        float bvv = -__builtin_inff();
        int   bii = SDIM;
        for (int s = tid; s < SDIM; s += NT) {
            float v = s_key[s];
            if (v > bvv) { bvv = v; bii = s; }
        }
        s_rv[tid] = bvv; s_ri[tid] = bii;
        __syncthreads();
        for (int off = NT / 2; off > 0; off >>= 1) {
            if (tid < off) {
                float v2 = s_rv[tid + off]; int i2 = s_ri[tid + off];
                if (v2 > s_rv[tid] || (v2 == s_rv[tid] && i2 < s_ri[tid])) {
                    s_rv[tid] = v2; s_ri[tid] = i2;
                }
            }
            __syncthreads();
        }
    }
    const int k = s_ri[0];

    // stable ranks via 64-bit keys: rank(j) = #{t : w_t < w_j}
    {
        const int j1 = tid + NT;
        const unsigned long long w0 = s_w[tid];
        const unsigned long long w1 = s_w[j1 < SDIM ? j1 : 0];
        int c0 = 0, c1 = 0;
        #pragma unroll 4
        for (int t = 0; t < SDIM; ++t) {
            unsigned long long wt = s_w[t];
            c0 += (wt < w0);
            c1 += (wt < w1);
        }
        s_pos[tid] = c0;
        if (j1 < SDIM) s_pos[j1] = c1;
    }
    __syncthreads();

    // j* : the element whose stable rank == k (ranks are a permutation)
    for (int j = tid; j < SDIM; j += NT)
        if (s_pos[j] == k) s_jstar = j;
    __syncthreads();

    if (tid == 0) {
        out_items[n] = (float)s_samp[s_jstar];
        ws_sim[n]    = (float)(s_pos[k] + 1) / (float)SDIM;
    }
    const int src = s_samp[k];
    if (tid < DDIM)
        out_feat[(long)n * DDIM + tid] = all_items[(long)src * DDIM + tid];
}

__global__ __launch_bounds__(NT) void rs_reduce(
    const float* __restrict__ ws_sim, float* __restrict__ out_scal, int N)
{
    __shared__ float s0[NT], s1[NT];
    int tid = threadIdx.x;
    float a = 0.f, m = 0.f;
    for (int i = tid; i < N; i += NT) {
        float sim = ws_sim[i];
        a += fabsf(sim - 0.5f);
        m += sim;
    }
    s0[tid] = a; s1[tid] = m;
    __syncthreads();
    for (int off = NT / 2; off > 0; off >>= 1) {
        if (tid < off) { s0[tid] += s0[tid + off]; s1[tid] += s1[tid + off]; }
        __syncthreads();
    }
    if (tid == 0) {
        out_scal[0] = s0[0] / (float)N;  // similarity_loss
        out_scal[1] = s1[0] / (float)N;  // mean(similarity)
    }
}

extern "C" void kernel_launch(void* const* d_in, const int* in_sizes, int n_in,
                              void* d_out, int out_size, void* d_ws, size_t ws_size,
                              hipStream_t stream) {
    const int*   need_replace  = (const int*)d_in[0];
    const float* union_feature = (const float*)d_in[1];
    const float* all_items     = (const float*)d_in[2];
    const int*   sample_items  = (const int*)d_in[3];
    const float* Wm            = (const float*)d_in[4];
    const float* bv            = (const float*)d_in[5];
    const float* gumbel_u      = (const float*)d_in[6];

    const int N = in_sizes[0] / 2;  // 4096

    float* out       = (float*)d_out;
    float* out_items = out;                       // N
    float* out_feat  = out + N;                   // N*64
    float* out_scal  = out + N + (long)N * DDIM;  // 2 scalars
    float* ws_sim    = (float*)d_ws;              // N floats

    rs_main<<<N, NT, 0, stream>>>(need_replace, union_feature, all_items,
                                  sample_items, Wm, bv, gumbel_u,
                                  out_items, out_feat, ws_sim);
    rs_reduce<<<1, NT, 0, stream>>>(ws_sim, out_scal, N);
}

// Round 3
// 81.443 us; speedup vs baseline: 3.0395x; 1.5651x over previous
//
#include <hip/hip_runtime.h>

#define SDIM 500
#define DDIM 64
#define NT   256

__device__ __forceinline__ unsigned int ford(float x) {
    unsigned int u = __float_as_uint(x);
    return u ^ ((unsigned)((int)u >> 31) | 0x80000000u);
}

__global__ __launch_bounds__(NT) void rs_main(
    const int* __restrict__ need_replace,    // (N,2)
    const float* __restrict__ union_feature, // (N,128)
    const float* __restrict__ all_items,     // (n_items,64)
    const int* __restrict__ sample_items,    // (n_users,500)
    const float* __restrict__ Wm,            // (64,128)
    const float* __restrict__ bv,            // (64)
    const float* __restrict__ gumbel_u,      // (N,500)
    float* __restrict__ out_items,           // (N)
    float* __restrict__ out_feat,            // (N,64)
    float* __restrict__ ws_sim)              // (N)
{
    __shared__ __align__(16) float s_uf[128];
    __shared__ __align__(16) float s_item[DDIM];
    __shared__ __align__(16) float s_uif[DDIM];
    __shared__ unsigned s_fv[SDIM];   // order-preserving uint of rank_score
    __shared__ float    s_key[SDIM];  // replace_score (raw, pre-gumbel)
    __shared__ int      s_samp[SDIM];
    __shared__ int      s_hist[256];
    __shared__ float    s_mv[4];
    __shared__ int      s_mi[4];
    __shared__ int      s_cnt4[4];
    __shared__ int      s_selb, s_selk, s_k, s_tn;
    __shared__ int      s_tbuf[64];

    const int n    = blockIdx.x;
    const int tid  = threadIdx.x;
    const int user = need_replace[2 * n];
    const int item = need_replace[2 * n + 1];

    // ---- stage inputs (coalesced) ----
    if (tid < 128) s_uf[tid] = union_feature[(long)n * 128 + tid];
    else if (tid < 128 + DDIM) s_item[tid - 128] = all_items[(long)item * DDIM + (tid - 128)];
    const int* samp_row = sample_items + (long)user * SDIM;
    for (int s = tid; s < SDIM; s += NT) s_samp[s] = samp_row[s];
    __syncthreads();

    // ---- uif = W @ uf + b : 4 lanes per output row ----
    {
        const int row = tid >> 2, part = tid & 3;
        const float4* wr4 = (const float4*)(Wm + (long)row * 128);
        const float4* uf4 = (const float4*)s_uf;
        float acc = 0.f;
        #pragma unroll
        for (int q = 0; q < 8; ++q) {
            float4 w4 = wr4[part + q * 4];
            float4 u4 = uf4[part + q * 4];
            acc += w4.x * u4.x + w4.y * u4.y + w4.z * u4.z + w4.w * u4.w;
        }
        acc += __shfl_xor(acc, 1);
        acc += __shfl_xor(acc, 2);
        if (part == 0) s_uif[row] = acc + bv[row];
    }
    __syncthreads();

    // ---- scores: 4 lanes per sample row (16 contiguous floats per lane) ----
    {
        const int part = tid & 3, quad = tid >> 2;
        const float4* i4 = (const float4*)s_item + part * 4;
        const float4* u4 = (const float4*)s_uif + part * 4;
        const float4 wiA = i4[0], wiB = i4[1], wiC = i4[2], wiD = i4[3];
        const float4 wuA = u4[0], wuB = u4[1], wuC = u4[2], wuD = u4[3];
        for (int s0 = 0; s0 < SDIM; s0 += NT / 4) {
            int s = s0 + quad;
            float a0 = 0.f, a1 = 0.f;
            if (s < SDIM) {
                const float4* fr = (const float4*)(all_items + (long)s_samp[s] * DDIM) + part * 4;
                float4 f0 = fr[0], f1 = fr[1], f2 = fr[2], f3 = fr[3];
                a0 = f0.x*wiA.x + f0.y*wiA.y + f0.z*wiA.z + f0.w*wiA.w
                   + f1.x*wiB.x + f1.y*wiB.y + f1.z*wiB.z + f1.w*wiB.w
                   + f2.x*wiC.x + f2.y*wiC.y + f2.z*wiC.z + f2.w*wiC.w
                   + f3.x*wiD.x + f3.y*wiD.y + f3.z*wiD.z + f3.w*wiD.w;
                a1 = f0.x*wuA.x + f0.y*wuA.y + f0.z*wuA.z + f0.w*wuA.w
                   + f1.x*wuB.x + f1.y*wuB.y + f1.z*wuB.z + f1.w*wuB.w
                   + f2.x*wuC.x + f2.y*wuC.y + f2.z*wuC.z + f2.w*wuC.w
                   + f3.x*wuD.x + f3.y*wuD.y + f3.z*wuD.z + f3.w*wuD.w;
            }
            a0 += __shfl_xor(a0, 1); a0 += __shfl_xor(a0, 2);
            a1 += __shfl_xor(a1, 1); a1 += __shfl_xor(a1, 2);
            if (s < SDIM && part == 0) { s_fv[s] = ford(a0); s_key[s] = a1; }
        }
    }
    __syncthreads();

    // ---- argmax of replace_score + gumbel (first-max tie-break) ----
    const float* gu_row = gumbel_u + (long)n * SDIM;
    {
        float bvv = -__builtin_inff();
        int   bii = SDIM;
        for (int s = tid; s < SDIM; s += NT) {
            float u = gu_row[s];
            float g = -logf(-logf(u * (1.0f - 2e-7f) + 1e-7f));
            float v = s_key[s] + g;
            if (v > bvv) { bvv = v; bii = s; }
        }
        #pragma unroll
        for (int off = 1; off < 64; off <<= 1) {
            float v2 = __shfl_xor(bvv, off); int i2 = __shfl_xor(bii, off);
            if (v2 > bvv || (v2 == bvv && i2 < bii)) { bvv = v2; bii = i2; }
        }
        if ((tid & 63) == 0) { s_mv[tid >> 6] = bvv; s_mi[tid >> 6] = bii; }
        __syncthreads();
        if (tid == 0) {
            float mv = s_mv[0]; int mi = s_mi[0];
            for (int w = 1; w < 4; ++w) {
                float v2 = s_mv[w]; int i2 = s_mi[w];
                if (v2 > mv || (v2 == mv && i2 < mi)) { mv = v2; mi = i2; }
            }
            s_k = mi;
        }
        __syncthreads();
    }
    const int k = s_k;

    // ---- overlap: feature output = all_items[samp[k]] ----
    {
        const int src = s_samp[k];
        if (tid < DDIM)
            out_feat[(long)n * DDIM + tid] = all_items[(long)src * DDIM + tid];
    }

    // ---- rank_k = #{t : key_t < key_k} (stable 64-bit order) ----
    int rank_k;
    {
        const unsigned fvk = s_fv[k];
        int cnt = 0;
        for (int s = tid; s < SDIM; s += NT) {
            unsigned v = s_fv[s];
            cnt += (int)((v < fvk) | ((v == fvk) & (s < k)));
        }
        #pragma unroll
        for (int off = 1; off < 64; off <<= 1) cnt += __shfl_xor(cnt, off);
        if ((tid & 63) == 0) s_cnt4[tid >> 6] = cnt;
        __syncthreads();
        rank_k = s_cnt4[0] + s_cnt4[1] + s_cnt4[2] + s_cnt4[3];
    }

    // ---- radix-select: j* = index of k-th smallest (stable) ----
    unsigned prefix = 0;
    int krem = k;
    for (int pass = 0; pass < 4; ++pass) {
        const int shift = 24 - 8 * pass;
        s_hist[tid] = 0;
        __syncthreads();
        const unsigned himask = pass ? (0xFFFFFFFFu << (shift + 8)) : 0u;
        for (int s = tid; s < SDIM; s += NT) {
            unsigned v = s_fv[s];
            if ((v & himask) == prefix) atomicAdd(&s_hist[(v >> shift) & 0xFF], 1);
        }
        __syncthreads();
        if (tid < 64) {
            int h0 = s_hist[4*tid], h1 = s_hist[4*tid+1], h2 = s_hist[4*tid+2], h3 = s_hist[4*tid+3];
            int s4 = h0 + h1 + h2 + h3, inc = s4;
            #pragma unroll
            for (int off = 1; off < 64; off <<= 1) {
                int t = __shfl_up(inc, off);
                if (tid >= off) inc += t;
            }
            int base = inc - s4;
            if (krem >= base && krem < inc) {
                if      (krem < base + h0)           { s_selb = 4*tid;   s_selk = krem - base; }
                else if (krem < base + h0 + h1)      { s_selb = 4*tid+1; s_selk = krem - base - h0; }
                else if (krem < base + h0 + h1 + h2) { s_selb = 4*tid+2; s_selk = krem - base - h0 - h1; }
                else                                 { s_selb = 4*tid+3; s_selk = krem - base - h0 - h1 - h2; }
            }
        }
        __syncthreads();
        prefix |= ((unsigned)s_selb) << shift;
        krem = s_selk;
        if (pass == 0) { if (tid == 0) s_tn = 0; }  // init tie counter under same sync cadence
    }

    // ---- resolve ties (equal fv) by original index: stable order ----
    __syncthreads();
    for (int s = tid; s < SDIM; s += NT) {
        if (s_fv[s] == prefix) {
            int slot = atomicAdd(&s_tn, 1);
            if (slot < 64) s_tbuf[slot] = s;
        }
    }
    __syncthreads();
    if (tid == 0) {
        int ntie = s_tn;
        int js = s_tbuf[0];
        if (ntie > 1) {
            for (int a = 0; a < ntie; ++a) {
                int c = s_tbuf[a], r = 0;
                for (int b2 = 0; b2 < ntie; ++b2) r += (int)(s_tbuf[b2] < c);
                if (r == krem) js = c;
            }
        }
        out_items[n] = (float)s_samp[js];
        ws_sim[n]    = (float)(rank_k + 1) / (float)SDIM;
    }
}

__global__ __launch_bounds__(NT) void rs_reduce(
    const float* __restrict__ ws_sim, float* __restrict__ out_scal, int N)
{
    __shared__ float s0[NT], s1[NT];
    int tid = threadIdx.x;
    float a = 0.f, m = 0.f;
    for (int i = tid; i < N; i += NT) {
        float sim = ws_sim[i];
        a += fabsf(sim - 0.5f);
        m += sim;
    }
    s0[tid] = a; s1[tid] = m;
    __syncthreads();
    for (int off = NT / 2; off > 0; off >>= 1) {
        if (tid < off) { s0[tid] += s0[tid + off]; s1[tid] += s1[tid + off]; }
        __syncthreads();
    }
    if (tid == 0) {
        out_scal[0] = s0[0] / (float)N;  // similarity_loss
        out_scal[1] = s1[0] / (float)N;  // mean(similarity)
    }
}

extern "C" void kernel_launch(void* const* d_in, const int* in_sizes, int n_in,
                              void* d_out, int out_size, void* d_ws, size_t ws_size,
                              hipStream_t stream) {
    const int*   need_replace  = (const int*)d_in[0];
    const float* union_feature = (const float*)d_in[1];
    const float* all_items     = (const float*)d_in[2];
    const int*   sample_items  = (const int*)d_in[3];
    const float* Wm            = (const float*)d_in[4];
    const float* bv            = (const float*)d_in[5];
    const float* gumbel_u      = (const float*)d_in[6];

    const int N = in_sizes[0] / 2;  // 4096

    float* out       = (float*)d_out;
    float* out_items = out;                       // N
    float* out_feat  = out + N;                   // N*64
    float* out_scal  = out + N + (long)N * DDIM;  // 2 scalars
    float* ws_sim    = (float*)d_ws;              // N floats

    rs_main<<<N, NT, 0, stream>>>(need_replace, union_feature, all_items,
                                  sample_items, Wm, bv, gumbel_u,
                                  out_items, out_feat, ws_sim);
    rs_reduce<<<1, NT, 0, stream>>>(ws_sim, out_scal, N);
}